// Round 2
// baseline (804.826 us; speedup 1.0000x reference)
//
#include <hip/hip_runtime.h>
#include <hip/hip_bf16.h>
#include <math.h>

#define NB   16
#define CIN  128
#define COUT 128
#define HH   56
#define WW   56
#define LL   (HH*WW)          // 3136
#define CHUNK 32
#define NCHUNK (CIN/CHUNK)

#define XS_SZ (CHUNK*3*58)    // 5568 floats: x window [cc][3 rows][58 cols]
#define WT_PITCH 129
#define WT_SZ (CHUNK*WT_PITCH)// 4128 floats: w tile [cc][oc] padded
#define EPI_SZ (COUT*WW)      // 7168

// ws: cos table [9*128] doubles, then sin table [9*128] doubles
__global__ void prep_tables(const float* __restrict__ bk, double* __restrict__ cs) {
    int i = blockIdx.x * blockDim.x + threadIdx.x;
    if (i < 9*COUT) {
        double v = (double)bk[i];
        cs[i]          = cos(v);
        cs[9*COUT + i] = sin(v);
    }
}

__global__ __launch_bounds__(512, 2)
void conv_phase_kernel(const float* __restrict__ x, const float* __restrict__ w,
                       const double* __restrict__ cs, const float* __restrict__ bias,
                       float* __restrict__ out) {
    __shared__ float smem[2*EPI_SZ];   // 57.3 KB; main loop uses xs+wt, epilogue reuses
    float* xs = smem;                  // [XS_SZ]
    float* wt = smem + XS_SZ;          // [WT_SZ]

    const int tid    = threadIdx.x;
    const int b      = blockIdx.x / HH;
    const int y      = blockIdx.x % HH;
    const int oc_grp = tid & 63;       // wave = 64 oc lanes, same px group
    const int px_grp = tid >> 6;       // 0..7 ; pixels px_grp + 8*i, i=0..6

    double acc_a[7][2], acc_b[7][2];
    #pragma unroll
    for (int i = 0; i < 7; i++) { acc_a[i][0]=0.0; acc_a[i][1]=0.0; acc_b[i][0]=0.0; acc_b[i][1]=0.0; }

    const float* xb = x + (size_t)b * CIN * LL;

    for (int ch = 0; ch < NCHUNK; ch++) {
        const int c0 = ch * CHUNK;
        __syncthreads();   // prior chunk's xs readers done
        // stage x window: rows y-1..y+1, cols -1..56 (zero padded), channels c0..c0+31
        for (int s = tid; s < XS_SZ; s += 512) {
            int cc  = s / 174;
            int rem = s - cc*174;
            int r   = rem / 58;
            int col = rem - r*58;
            int row  = y + r - 1;
            int gcol = col - 1;
            float v = 0.0f;
            if ((unsigned)row < HH && (unsigned)gcol < WW)
                v = xb[(size_t)(c0+cc)*LL + row*WW + gcol];
            xs[s] = v;
        }
        for (int k = 0; k < 9; k++) {
            const int dy = k / 3, dx = k - dy*3;
            __syncthreads();   // xs visible / previous wt readers done
            // stage w[k][oc][c0..c0+31] transposed -> wt[cc][oc]
            for (int s = tid; s < CHUNK*COUT; s += 512) {
                int oc = s >> 5;
                int cc = s & 31;
                wt[cc*WT_PITCH + oc] = w[k*(COUT*CIN) + oc*CIN + c0 + cc];
            }
            __syncthreads();

            double dot[7][2];
            #pragma unroll
            for (int i = 0; i < 7; i++) { dot[i][0]=0.0; dot[i][1]=0.0; }

            #pragma unroll 4
            for (int cc = 0; cc < CHUNK; cc++) {
                float xv[7];
                #pragma unroll
                for (int i = 0; i < 7; i++)
                    xv[i] = xs[cc*174 + dy*58 + px_grp + 8*i + dx];
                float w0 = wt[cc*WT_PITCH + oc_grp];
                float w1 = wt[cc*WT_PITCH + oc_grp + 64];
                #pragma unroll
                for (int i = 0; i < 7; i++) {
                    dot[i][0] = fma((double)xv[i], (double)w0, dot[i][0]);
                    dot[i][1] = fma((double)xv[i], (double)w1, dot[i][1]);
                }
            }
            // fold tap k into a/b with cos/sin (fp64 tables)
            double ck0 = cs[k*COUT + oc_grp];
            double ck1 = cs[k*COUT + oc_grp + 64];
            double sk0 = cs[9*COUT + k*COUT + oc_grp];
            double sk1 = cs[9*COUT + k*COUT + oc_grp + 64];
            #pragma unroll
            for (int i = 0; i < 7; i++) {
                acc_a[i][0] = fma(ck0, dot[i][0], acc_a[i][0]);
                acc_a[i][1] = fma(ck1, dot[i][1], acc_a[i][1]);
                acc_b[i][0] = fma(sk0, dot[i][0], acc_b[i][0]);
                acc_b[i][1] = fma(sk1, dot[i][1], acc_b[i][1]);
            }
        }
    }

    // ---- epilogue: theta / magnitude, transpose via LDS, coalesced fp32 stores ----
    __syncthreads();
    float* conv_s  = smem;
    float* theta_s = smem + EPI_SZ;
    const double eps = 1e-05;
    const double PI  = 3.14159265358979323846;

    #pragma unroll
    for (int j = 0; j < 2; j++) {
        int oc = oc_grp + 64*j;
        float bsv = bias[oc];
        #pragma unroll
        for (int i = 0; i < 7; i++) {
            int px = px_grp + 8*i;
            double av = acc_a[i][j], bv = acc_b[i][j];
            bool ag = av > 0.0, bg = bv > 0.0;
            bool eq = (ag == bg);
            // ratios & branch selection in fp64 (sign-exact); transcendentals fp32
            double ratio = eq ? (bv / (av + eps)) : (av / (bv + eps));
            float at = atanf((float)ratio);
            if (!eq) at = -at;
            double peak = eq ? (ag ? PI*0.5 : -PI*0.5) : (bg ? 0.0 : -PI);
            float th = (float)peak - at;
            float o  = sinf(th)*(float)av + cosf(th)*(float)bv + bsv;
            conv_s[oc*WW + px]  = o;
            theta_s[oc*WW + px] = th * (float)(1.0/PI);
        }
    }
    __syncthreads();
    size_t obase = ((size_t)b*(2*COUT))*LL + (size_t)y*WW;
    for (int s = tid; s < EPI_SZ; s += 512) {
        int oc = s / WW;
        int px = s - oc*WW;
        out[obase + (size_t)oc*LL + px]          = conv_s[s];
        out[obase + (size_t)(oc + COUT)*LL + px] = theta_s[s];
    }
}

extern "C" void kernel_launch(void* const* d_in, const int* in_sizes, int n_in,
                              void* d_out, int out_size, void* d_ws, size_t ws_size,
                              hipStream_t stream) {
    const float* x    = (const float*)d_in[0];  // (16,128,56,56)
    const float* w    = (const float*)d_in[1];  // (1,9,128,128)
    const float* bk   = (const float*)d_in[2];  // (1,9,1,128,1) -> [k*128+oc]
    const float* bias = (const float*)d_in[3];  // (128,)
    double* cs = (double*)d_ws;                 // 2*9*128 doubles = 18 KB
    float* out = (float*)d_out;

    hipLaunchKernelGGL(prep_tables, dim3(5), dim3(256), 0, stream, bk, cs);
    hipLaunchKernelGGL(conv_phase_kernel, dim3(NB*HH), dim3(512), 0, stream,
                       x, w, cs, bias, out);
}